// Round 1
// baseline (304.958 us; speedup 1.0000x reference)
//
#include <hip/hip_runtime.h>
#include <cstdint>

// ContextualAttention on MI355X (gfx950), all-bf16 MFMA pipeline.
// B=4 TI=TC=1024 T=2048 E=1024 H=16 D=64. fp32 in/out, bf16 compute.
//
// Pipeline (7 launches):
//   cast_concat: x||context -> bf16 xc [B,T,E]
//   cast_w:      Wq,Wk,Wv,Wu -> bf16
//   gemm_bt<0>:  Q = xc_rows(x)*Wq^T, fused head-LN+scale epilogue -> bf16 [4096,1024]
//   gemm_bt<0>:  K = xc*Wk^T, fused head-LN+scale -> bf16 [8192,1024]
//   gemm_bt<1>:  V = xc*Wv^T, epilogue writes TRANSPOSED Vt[b,h,d,t] bf16
//   attn:        flash attention, swapped QK^T (S^T), P in registers
//   gemm_bt<2>:  out = AO*Wu^T + bu, fp32 -> d_out

typedef unsigned short u16;
typedef __attribute__((ext_vector_type(8))) short bf16x8;
typedef __attribute__((ext_vector_type(4))) float f32x4;
typedef __attribute__((ext_vector_type(4))) unsigned short u16x4;

#define GLDS(gsrc, ldst)                                                              \
  __builtin_amdgcn_global_load_lds(                                                   \
      (const __attribute__((address_space(1))) unsigned int*)(gsrc),                  \
      (__attribute__((address_space(3))) unsigned int*)(ldst), 16, 0, 0)

__device__ __forceinline__ u16 f2bf(float x) {
  unsigned int u = __float_as_uint(x);
  u += 0x7fffu + ((u >> 16) & 1u);
  return (u16)(u >> 16);
}

__device__ __forceinline__ f32x4 mfma16(bf16x8 a, bf16x8 b, f32x4 c) {
  return __builtin_amdgcn_mfma_f32_16x16x32_bf16(a, b, c, 0, 0, 0);
}

// ---------------- cast kernels ----------------

__global__ __launch_bounds__(256) void cast_concat(const float* __restrict__ x,
                                                   const float* __restrict__ c,
                                                   u16* __restrict__ o) {
  const int n4 = (8 << 20) / 4;  // B*T*E / 4
  for (int i = blockIdx.x * blockDim.x + threadIdx.x; i < n4; i += gridDim.x * blockDim.x) {
    int elem = i * 4;
    int b = elem >> 21;
    int rem = elem & ((1 << 21) - 1);
    int r = rem >> 10;
    int e = rem & 1023;
    const float* src = (r < 1024) ? (x + ((((size_t)(b << 10)) + r) << 10) + e)
                                  : (c + ((((size_t)(b << 10)) + (r - 1024)) << 10) + e);
    float4 v = *(const float4*)src;
    u16x4 ov;
    ov.x = f2bf(v.x); ov.y = f2bf(v.y); ov.z = f2bf(v.z); ov.w = f2bf(v.w);
    *(u16x4*)(o + elem) = ov;
  }
}

__global__ __launch_bounds__(256) void cast_w(const float* __restrict__ w0,
                                              const float* __restrict__ w1,
                                              const float* __restrict__ w2,
                                              const float* __restrict__ w3,
                                              u16* __restrict__ o) {
  const int n4 = (4 << 20) / 4;
  for (int i = blockIdx.x * blockDim.x + threadIdx.x; i < n4; i += gridDim.x * blockDim.x) {
    int elem = i * 4;
    int sel = elem >> 20;
    int loc = elem & ((1 << 20) - 1);
    const float* s = (sel == 0) ? w0 : (sel == 1) ? w1 : (sel == 2) ? w2 : w3;
    float4 v = *(const float4*)(s + loc);
    u16x4 ov;
    ov.x = f2bf(v.x); ov.y = f2bf(v.y); ov.z = f2bf(v.z); ov.w = f2bf(v.w);
    *(u16x4*)(o + elem) = ov;
  }
}

// ---------------- GEMM: C = A * Bw^T (both bf16 row-major, K contiguous) ----------------
// EPI 0: per-64-col head LayerNorm(gamma=P0, beta=P1) * oscale -> bf16 Ob row-major
// EPI 1: bf16 transposed write: Ob = Vt[b,h,d,t]  (M rows are b*2048+t, cols h*64+d)
// EPI 2: fp32 + bias(P0) -> Of row-major

template <int EPI>
__global__ __launch_bounds__(256)
void gemm_bt(const u16* __restrict__ A, const u16* __restrict__ Bw,
             u16* __restrict__ Ob, float* __restrict__ Of,
             const float* __restrict__ P0, const float* __restrict__ P1,
             int M, int N, int K, int rpbo, int rpbi, float oscale) {
  __shared__ alignas(16) u16 lA[128 * 32];
  __shared__ alignas(16) u16 lB[128 * 32];
  const int tid = threadIdx.x;
  const int wv = tid >> 6, l = tid & 63, g = l >> 4, c16 = l & 15;
  const int wr = wv >> 1, wc = wv & 1;
  const int m0 = blockIdx.x * 128, n0 = blockIdx.y * 128;
  const int arow0 = (m0 / rpbo) * rpbi + (m0 % rpbo);

  f32x4 acc[4][4];
  const f32x4 z4 = {0.f, 0.f, 0.f, 0.f};
#pragma unroll
  for (int i = 0; i < 4; ++i)
#pragma unroll
    for (int j = 0; j < 4; ++j) acc[i][j] = z4;

  // staging: 16B chunks, linear LDS dest (chunk = tid), XOR-swizzled global source
  const int srow = tid >> 2;
  const int scA = (tid & 3) ^ (srow & 3);
  const u16* aSrc = A + (size_t)(arow0 + srow) * K + scA * 8;
  const u16* bSrc = Bw + (size_t)(n0 + srow) * K + scA * 8;
  char* ldA = (char*)lA;
  char* ldB = (char*)lB;
  const int lof = wv * 1024;

  const int ksteps = K >> 5;
  for (int kt = 0; kt < ksteps; ++kt) {
    const int kof = kt << 5;
    GLDS(aSrc + kof, ldA + lof);
    GLDS(aSrc + (size_t)64 * K + kof, ldA + 4096 + lof);
    GLDS(bSrc + kof, ldB + lof);
    GLDS(bSrc + (size_t)64 * K + kof, ldB + 4096 + lof);
    __syncthreads();
    bf16x8 af[4], bfr[4];
#pragma unroll
    for (int mi = 0; mi < 4; ++mi) {
      int row = wr * 64 + mi * 16 + c16;
      af[mi] = *(const bf16x8*)(ldA + row * 64 + ((g * 16) ^ ((row & 3) << 4)));
    }
#pragma unroll
    for (int ni = 0; ni < 4; ++ni) {
      int row = wc * 64 + ni * 16 + c16;
      bfr[ni] = *(const bf16x8*)(ldB + row * 64 + ((g * 16) ^ ((row & 3) << 4)));
    }
#pragma unroll
    for (int mi = 0; mi < 4; ++mi)
#pragma unroll
      for (int ni = 0; ni < 4; ++ni)
        acc[mi][ni] = mfma16(af[mi], bfr[ni], acc[mi][ni]);
    __syncthreads();
  }

  // ---- epilogues ----  C layout (verified): col = l&15, row = (l>>4)*4 + reg
  if constexpr (EPI == 2) {
#pragma unroll
    for (int ni = 0; ni < 4; ++ni) {
      int col = n0 + wc * 64 + ni * 16 + c16;
      float bv = P0[col];
#pragma unroll
      for (int mi = 0; mi < 4; ++mi) {
        int row = m0 + wr * 64 + mi * 16 + g * 4;
        float* dst = Of + (size_t)row * N + col;
#pragma unroll
        for (int r = 0; r < 4; ++r) dst[(size_t)r * N] = acc[mi][ni][r] + bv;
      }
    }
  } else if constexpr (EPI == 1) {
    // write Vt[((b*16+h)*64+d)*2048 + t]; m = b*2048+t, col = h*64+d
#pragma unroll
    for (int ni = 0; ni < 4; ++ni) {
      int col = n0 + wc * 64 + ni * 16 + c16;
      int hh = col >> 6, dd = col & 63;
#pragma unroll
      for (int mi = 0; mi < 4; ++mi) {
        int m = m0 + wr * 64 + mi * 16 + g * 4;
        int bb = m >> 11, tt = m & 2047;
        u16x4 o;
#pragma unroll
        for (int r = 0; r < 4; ++r) o[r] = f2bf(acc[mi][ni][r]);
        *(u16x4*)(Ob + ((size_t)((bb * 16 + hh) * 64 + dd)) * 2048 + tt) = o;
      }
    }
  } else {
    // EPI==0: LayerNorm over the wave's 64-col head segment, per row.
    // Row (mi, g, r) is held by the 16 lanes of group g (c16=0..15) across ni.
#pragma unroll
    for (int mi = 0; mi < 4; ++mi) {
      float sum[4], sq[4];
#pragma unroll
      for (int r = 0; r < 4; ++r) {
        float s = 0.f, q = 0.f;
#pragma unroll
        for (int ni = 0; ni < 4; ++ni) {
          float v = acc[mi][ni][r];
          s += v;
          q += v * v;
        }
#pragma unroll
        for (int msk = 1; msk < 16; msk <<= 1) {
          s += __shfl_xor(s, msk);
          q += __shfl_xor(q, msk);
        }
        sum[r] = s;
        sq[r] = q;
      }
#pragma unroll
      for (int ni = 0; ni < 4; ++ni) {
        int dloc = ni * 16 + c16;  // position within the 64-wide head
        int colg = n0 + wc * 64 + ni * 16 + c16;
        float gv = P0[dloc], bv = P1[dloc];
#pragma unroll
        for (int r = 0; r < 4; ++r) {
          float mean = sum[r] * (1.f / 64.f);
          float var = sq[r] * (1.f / 64.f) - mean * mean;
          float y = (acc[mi][ni][r] - mean) * rsqrtf(var + 1e-5f) * gv + bv;
          int row = m0 + wr * 64 + mi * 16 + g * 4 + r;
          Ob[(size_t)row * N + colg] = f2bf(y * oscale);
        }
      }
    }
  }
}

// ---------------- flash attention ----------------
// block = (qt, h, b): 4 waves x 16 q-rows, KV tiles of 64.
// Swapped QK^T: S^T = mfma(A=K_tile, B=Q) -> lane holds S[q=l&15][kv=nk*16+(l>>4)*4+r].
// PV: O = mfma(A=Vt_tile(m=d,k=kv), B=P^T(n=q)) with P^T B-frag built by ds_bpermute.

__global__ __launch_bounds__(256)
void attn_kernel(const u16* __restrict__ Q, const u16* __restrict__ Kb,
                 const u16* __restrict__ Vt, u16* __restrict__ AO) {
  __shared__ alignas(16) u16 lK[64 * 64];
  __shared__ alignas(16) u16 lV[64 * 64];
  const int tid = threadIdx.x;
  const int wv = tid >> 6, l = tid & 63, g = l >> 4, c16 = l & 15;
  const int b = blockIdx.z, h = blockIdx.y, qt = blockIdx.x;
  const int qrow = (b << 10) + (qt << 6) + (wv << 4) + c16;

  const u16* qp = Q + (size_t)qrow * 1024 + h * 64 + g * 8;
  bf16x8 qf0 = *(const bf16x8*)(qp);
  bf16x8 qf1 = *(const bf16x8*)(qp + 32);

  const f32x4 z4 = {0.f, 0.f, 0.f, 0.f};
  f32x4 acc_o[4];
#pragma unroll
  for (int i = 0; i < 4; ++i) acc_o[i] = z4;
  float m_run = -3.0e38f, l_run = 0.f;

  const u16* Kbase = Kb + (size_t)(b * 2048) * 1024 + (size_t)h * 64;
  const u16* Vbase = Vt + (size_t)((b * 16 + h) * 64) * 2048;
  const int prow = tid >> 3, pch = tid & 7;
  const int sc = pch ^ (prow & 7);  // XOR-swizzled source chunk (rows are 128B)
  const int lof = wv * 1024;

  for (int t32 = 0; t32 < 32; ++t32) {
    const int kv0 = t32 << 6;
    GLDS(Kbase + (size_t)(kv0 + prow) * 1024 + sc * 8, (char*)lK + lof);
    GLDS(Kbase + (size_t)(kv0 + prow + 32) * 1024 + sc * 8, (char*)lK + 4096 + lof);
    GLDS(Vbase + (size_t)prow * 2048 + kv0 + sc * 8, (char*)lV + lof);
    GLDS(Vbase + (size_t)(prow + 32) * 2048 + kv0 + sc * 8, (char*)lV + 4096 + lof);
    __syncthreads();

    // S^T = K . Q^T
    f32x4 s[4];
#pragma unroll
    for (int nk = 0; nk < 4; ++nk) s[nk] = z4;
#pragma unroll
    for (int nk = 0; nk < 4; ++nk) {
      int row = nk * 16 + c16;
      int swz = (row & 7) << 4;
      bf16x8 ka0 = *(const bf16x8*)((char*)lK + row * 128 + ((g * 16) ^ swz));
      bf16x8 ka1 = *(const bf16x8*)((char*)lK + row * 128 + ((64 + g * 16) ^ swz));
      s[nk] = mfma16(ka0, qf0, s[nk]);
      s[nk] = mfma16(ka1, qf1, s[nk]);
    }

    // online softmax over kv (row = fixed q = c16; reduce across the 4 lane-groups)
    float tm = -3.0e38f;
#pragma unroll
    for (int nk = 0; nk < 4; ++nk)
#pragma unroll
      for (int r = 0; r < 4; ++r) tm = fmaxf(tm, s[nk][r]);
    tm = fmaxf(tm, __shfl_xor(tm, 16));
    tm = fmaxf(tm, __shfl_xor(tm, 32));
    float mnew = fmaxf(m_run, tm);
    float corr = __expf(m_run - mnew);
    float ts = 0.f;
#pragma unroll
    for (int nk = 0; nk < 4; ++nk)
#pragma unroll
      for (int r = 0; r < 4; ++r) {
        float p = __expf(s[nk][r] - mnew);
        s[nk][r] = p;
        ts += p;
      }
    ts += __shfl_xor(ts, 16);
    ts += __shfl_xor(ts, 32);
    l_run = l_run * corr + ts;
    m_run = mnew;
#pragma unroll
    for (int nd = 0; nd < 4; ++nd) acc_o[nd] *= corr;

    // pack P to bf16 pairs: pk[nk][h2] = {r=2h2, r=2h2+1} (consecutive kv)
    unsigned int pk[4][2];
#pragma unroll
    for (int nk = 0; nk < 4; ++nk) {
      pk[nk][0] = (unsigned int)f2bf(s[nk][0]) | ((unsigned int)f2bf(s[nk][1]) << 16);
      pk[nk][1] = (unsigned int)f2bf(s[nk][2]) | ((unsigned int)f2bf(s[nk][3]) << 16);
    }

    // PV: O[q][d] += P[q][kv] * V[kv][d], kv chunks of 32
#pragma unroll
    for (int c = 0; c < 2; ++c) {
      union {
        unsigned int w[4];
        bf16x8 v;
      } pb;
#pragma unroll
      for (int wj = 0; wj < 4; ++wj) {
        int srcl = ((l & 16) << 1) + ((wj & 2) << 3) + c16;
        unsigned int lo = (unsigned int)__shfl((int)pk[c * 2][wj & 1], srcl);
        unsigned int hi = (unsigned int)__shfl((int)pk[c * 2 + 1][wj & 1], srcl);
        pb.w[wj] = (l & 32) ? hi : lo;
      }
#pragma unroll
      for (int nd = 0; nd < 4; ++nd) {
        int row = nd * 16 + c16;
        int swz = (row & 7) << 4;
        bf16x8 va = *(const bf16x8*)((char*)lV + row * 128 + (((c << 6) + (g << 4)) ^ swz));
        acc_o[nd] = mfma16(va, pb.v, acc_o[nd]);
      }
    }
    __syncthreads();
  }

  float invl = 1.f / l_run;
#pragma unroll
  for (int nd = 0; nd < 4; ++nd) {
    u16x4 o;
#pragma unroll
    for (int r = 0; r < 4; ++r) o[r] = f2bf(acc_o[nd][r] * invl);
    *(u16x4*)(AO + (size_t)qrow * 1024 + h * 64 + nd * 16 + (g << 2)) = o;
  }
}

// ---------------- launch ----------------

extern "C" void kernel_launch(void* const* d_in, const int* in_sizes, int n_in,
                              void* d_out, int out_size, void* d_ws, size_t ws_size,
                              hipStream_t stream) {
  const float* x = (const float*)d_in[0];
  const float* ctx = (const float*)d_in[1];
  const float* Wq = (const float*)d_in[2];
  const float* Wk = (const float*)d_in[3];
  const float* Wv = (const float*)d_in[4];
  const float* Wu = (const float*)d_in[5];
  const float* bu = (const float*)d_in[6];
  const float* qg = (const float*)d_in[7];
  const float* qb = (const float*)d_in[8];
  const float* kg = (const float*)d_in[9];
  const float* kb = (const float*)d_in[10];
  float* out = (float*)d_out;

  char* w = (char*)d_ws;
  u16* XCB = (u16*)(w);                       // 16 MB: xc bf16 [B,T,E]
  u16* WQB = (u16*)(w + ((size_t)16 << 20));  // 2 MB each, contiguous
  u16* WKB = (u16*)(w + ((size_t)18 << 20));
  u16* WVB = (u16*)(w + ((size_t)20 << 20));
  u16* WUB = (u16*)(w + ((size_t)22 << 20));
  u16* QBB = (u16*)(w + ((size_t)24 << 20));  // 8 MB
  u16* KBB = (u16*)(w + ((size_t)32 << 20));  // 16 MB
  u16* VT = (u16*)(w + ((size_t)48 << 20));   // 16 MB
  u16* AO = (u16*)(w + ((size_t)64 << 20));   // 8 MB  (total 72 MB)

  const float invs = 0.17677669529663687f;  // 1024^-0.25

  cast_concat<<<2048, 256, 0, stream>>>(x, ctx, XCB);
  cast_w<<<1024, 256, 0, stream>>>(Wq, Wk, Wv, Wu, WQB);

  // Q: rows of x mapped into xc (rpb_out=1024 -> rpb_in=2048)
  gemm_bt<0><<<dim3(32, 8), 256, 0, stream>>>(XCB, WQB, QBB, nullptr, qg, qb,
                                              4096, 1024, 1024, 1024, 2048, invs);
  gemm_bt<0><<<dim3(64, 8), 256, 0, stream>>>(XCB, WKB, KBB, nullptr, kg, kb,
                                              8192, 1024, 1024, 2048, 2048, invs);
  gemm_bt<1><<<dim3(64, 8), 256, 0, stream>>>(XCB, WVB, VT, nullptr, nullptr, nullptr,
                                              8192, 1024, 1024, 2048, 2048, 1.f);

  attn_kernel<<<dim3(16, 16, 4), 256, 0, stream>>>(QBB, KBB, VT, AO);

  gemm_bt<2><<<dim3(32, 8), 256, 0, stream>>>(AO, WUB, nullptr, out, bu, nullptr,
                                              4096, 1024, 1024, 4096, 4096, 1.f);
}

// Round 2
// 302.589 us; speedup vs baseline: 1.0078x; 1.0078x over previous
//
#include <hip/hip_runtime.h>
#include <cstdint>

// ContextualAttention on MI355X (gfx950), all-bf16 MFMA pipeline.
// R1: 32x32 MFMA flash-attn (m214 structure), conflict-free column-chunk LDS,
//     exp2-domain softmax w/ defer-max, 2-phase prefetch in attn + all GEMMs.

typedef unsigned short u16;
typedef __attribute__((ext_vector_type(8))) short bf16x8;
typedef __attribute__((ext_vector_type(4))) float f32x4;
typedef __attribute__((ext_vector_type(16))) float f32x16;
typedef __attribute__((ext_vector_type(4))) unsigned short u16x4;

#define GLDS(gsrc, ldst)                                                              \
  __builtin_amdgcn_global_load_lds(                                                   \
      (const __attribute__((address_space(1))) unsigned int*)(gsrc),                  \
      (__attribute__((address_space(3))) unsigned int*)(ldst), 16, 0, 0)

__device__ __forceinline__ u16 f2bf(float x) {
  unsigned int u = __float_as_uint(x);
  u += 0x7fffu + ((u >> 16) & 1u);
  return (u16)(u >> 16);
}

__device__ __forceinline__ f32x4 mfma16(bf16x8 a, bf16x8 b, f32x4 c) {
  return __builtin_amdgcn_mfma_f32_16x16x32_bf16(a, b, c, 0, 0, 0);
}
__device__ __forceinline__ f32x16 mfma32(bf16x8 a, bf16x8 b, f32x16 c) {
  return __builtin_amdgcn_mfma_f32_32x32x16_bf16(a, b, c, 0, 0, 0);
}

// ---------------- cast kernels ----------------

__global__ __launch_bounds__(256) void cast_concat(const float* __restrict__ x,
                                                   const float* __restrict__ c,
                                                   u16* __restrict__ o) {
  const int n4 = (8 << 20) / 4;  // B*T*E / 4
  for (int i = blockIdx.x * blockDim.x + threadIdx.x; i < n4; i += gridDim.x * blockDim.x) {
    int elem = i * 4;
    int b = elem >> 21;
    int rem = elem & ((1 << 21) - 1);
    int r = rem >> 10;
    int e = rem & 1023;
    const float* src = (r < 1024) ? (x + ((((size_t)(b << 10)) + r) << 10) + e)
                                  : (c + ((((size_t)(b << 10)) + (r - 1024)) << 10) + e);
    float4 v = *(const float4*)src;
    u16x4 ov;
    ov.x = f2bf(v.x); ov.y = f2bf(v.y); ov.z = f2bf(v.z); ov.w = f2bf(v.w);
    *(u16x4*)(o + elem) = ov;
  }
}

__global__ __launch_bounds__(256) void cast_w(const float* __restrict__ w0,
                                              const float* __restrict__ w1,
                                              const float* __restrict__ w2,
                                              const float* __restrict__ w3,
                                              u16* __restrict__ o) {
  const int n4 = (4 << 20) / 4;
  for (int i = blockIdx.x * blockDim.x + threadIdx.x; i < n4; i += gridDim.x * blockDim.x) {
    int elem = i * 4;
    int sel = elem >> 20;
    int loc = elem & ((1 << 20) - 1);
    const float* s = (sel == 0) ? w0 : (sel == 1) ? w1 : (sel == 2) ? w2 : w3;
    float4 v = *(const float4*)(s + loc);
    u16x4 ov;
    ov.x = f2bf(v.x); ov.y = f2bf(v.y); ov.z = f2bf(v.z); ov.w = f2bf(v.w);
    *(u16x4*)(o + elem) = ov;
  }
}

// ---------------- GEMM: C = A * Bw^T, 128x128 tile, BK=32, 2-phase dbuf ----------------
// EPI 0: per-64-col head LayerNorm(gamma=P0, beta=P1) * oscale -> bf16 Ob row-major
// EPI 1: bf16 transposed write: Ob = Vt[b,h,d,t]
// EPI 2: fp32 + bias(P0) -> Of row-major

template <int EPI>
__global__ __launch_bounds__(256)
void gemm_bt(const u16* __restrict__ A, const u16* __restrict__ Bw,
             u16* __restrict__ Ob, float* __restrict__ Of,
             const float* __restrict__ P0, const float* __restrict__ P1,
             int M, int N, int K, int rpbo, int rpbi, float oscale) {
  __shared__ alignas(16) u16 lA[2][128 * 32];
  __shared__ alignas(16) u16 lB[2][128 * 32];
  const int tid = threadIdx.x;
  const int wv = tid >> 6, l = tid & 63, g = l >> 4, c16 = l & 15;
  const int wr = wv >> 1, wc = wv & 1;
  const int m0 = blockIdx.x * 128, n0 = blockIdx.y * 128;
  const int arow0 = (m0 / rpbo) * rpbi + (m0 % rpbo);

  f32x4 acc[4][4];
  const f32x4 z4 = {0.f, 0.f, 0.f, 0.f};
#pragma unroll
  for (int i = 0; i < 4; ++i)
#pragma unroll
    for (int j = 0; j < 4; ++j) acc[i][j] = z4;

  // staging: 16B chunks, linear LDS dest, XOR-swizzled global source
  const int srow = tid >> 2;
  const int scA = (tid & 3) ^ (srow & 3);
  const u16* aSrc = A + (size_t)(arow0 + srow) * K + scA * 8;
  const u16* bSrc = Bw + (size_t)(n0 + srow) * K + scA * 8;
  char* ldA = (char*)lA;
  char* ldB = (char*)lB;
  const int lof = wv * 1024;

  const int ksteps = K >> 5;
#define STAGE_G(bi, kof)                                   \
  {                                                        \
    char* dA = ldA + (bi)*8192 + lof;                      \
    char* dB = ldB + (bi)*8192 + lof;                      \
    GLDS(aSrc + (kof), dA);                                \
    GLDS(aSrc + (size_t)64 * K + (kof), dA + 4096);        \
    GLDS(bSrc + (kof), dB);                                \
    GLDS(bSrc + (size_t)64 * K + (kof), dB + 4096);        \
  }

  STAGE_G(0, 0);
  __syncthreads();
  int buf = 0;
  for (int kt = 0; kt < ksteps; ++kt) {
    if (kt + 1 < ksteps) STAGE_G(buf ^ 1, (kt + 1) << 5);
    const char* bA = ldA + buf * 8192;
    const char* bB = ldB + buf * 8192;
    bf16x8 af[4], bfr[4];
#pragma unroll
    for (int mi = 0; mi < 4; ++mi) {
      int row = wr * 64 + mi * 16 + c16;
      af[mi] = *(const bf16x8*)(bA + row * 64 + ((g * 16) ^ ((row & 3) << 4)));
    }
#pragma unroll
    for (int ni = 0; ni < 4; ++ni) {
      int row = wc * 64 + ni * 16 + c16;
      bfr[ni] = *(const bf16x8*)(bB + row * 64 + ((g * 16) ^ ((row & 3) << 4)));
    }
#pragma unroll
    for (int mi = 0; mi < 4; ++mi)
#pragma unroll
      for (int ni = 0; ni < 4; ++ni)
        acc[mi][ni] = mfma16(af[mi], bfr[ni], acc[mi][ni]);
    __syncthreads();
    buf ^= 1;
  }
#undef STAGE_G

  // ---- epilogues ----  C layout: col = l&15, row = (l>>4)*4 + reg
  if constexpr (EPI == 2) {
#pragma unroll
    for (int ni = 0; ni < 4; ++ni) {
      int col = n0 + wc * 64 + ni * 16 + c16;
      float bv = P0[col];
#pragma unroll
      for (int mi = 0; mi < 4; ++mi) {
        int row = m0 + wr * 64 + mi * 16 + g * 4;
        float* dst = Of + (size_t)row * N + col;
#pragma unroll
        for (int r = 0; r < 4; ++r) dst[(size_t)r * N] = acc[mi][ni][r] + bv;
      }
    }
  } else if constexpr (EPI == 1) {
#pragma unroll
    for (int ni = 0; ni < 4; ++ni) {
      int col = n0 + wc * 64 + ni * 16 + c16;
      int hh = col >> 6, dd = col & 63;
#pragma unroll
      for (int mi = 0; mi < 4; ++mi) {
        int m = m0 + wr * 64 + mi * 16 + g * 4;
        int bb = m >> 11, tt = m & 2047;
        u16x4 o;
#pragma unroll
        for (int r = 0; r < 4; ++r) o[r] = f2bf(acc[mi][ni][r]);
        *(u16x4*)(Ob + ((size_t)((bb * 16 + hh) * 64 + dd)) * 2048 + tt) = o;
      }
    }
  } else {
#pragma unroll
    for (int mi = 0; mi < 4; ++mi) {
      float sum[4], sq[4];
#pragma unroll
      for (int r = 0; r < 4; ++r) {
        float s = 0.f, q = 0.f;
#pragma unroll
        for (int ni = 0; ni < 4; ++ni) {
          float v = acc[mi][ni][r];
          s += v;
          q += v * v;
        }
#pragma unroll
        for (int msk = 1; msk < 16; msk <<= 1) {
          s += __shfl_xor(s, msk);
          q += __shfl_xor(q, msk);
        }
        sum[r] = s;
        sq[r] = q;
      }
#pragma unroll
      for (int ni = 0; ni < 4; ++ni) {
        int dloc = ni * 16 + c16;
        int colg = n0 + wc * 64 + ni * 16 + c16;
        float gv = P0[dloc], bv = P1[dloc];
#pragma unroll
        for (int r = 0; r < 4; ++r) {
          float mean = sum[r] * (1.f / 64.f);
          float var = sq[r] * (1.f / 64.f) - mean * mean;
          float y = (acc[mi][ni][r] - mean) * rsqrtf(var + 1e-5f) * gv + bv;
          int row = m0 + wr * 64 + mi * 16 + g * 4 + r;
          Ob[(size_t)row * N + colg] = f2bf(y * oscale);
        }
      }
    }
  }
}

// ---------------- flash attention, 32x32 MFMA ----------------
// block = 256 thr = 4 waves; wave owns 32 q-rows; block = 128 q-rows of one (b,h).
// KV tile 64, double-buffered. LDS column-chunk layout (conflict-free, linear GLDS):
//   K: addr = dchunk*1024 + kv*16   (dchunk = d/8,  d = head dim 64)
//   V: addr = kvchunk*1024 + d*16   (kvchunk = kv/8)
// QK^T swapped: s[kvh] = mfma32(A=K[kv half], B=Q) -> S^T: col q=l&31,
//   row kv = (r&3)+8*(r>>2)+4*(l>>5). Softmax in exp2-domain (log2e folded into Q).

__global__ __launch_bounds__(256)
void attn_kernel(const u16* __restrict__ Q, const u16* __restrict__ Kb,
                 const u16* __restrict__ Vt, u16* __restrict__ AO) {
  __shared__ alignas(16) u16 lK[2][4096];
  __shared__ alignas(16) u16 lV[2][4096];
  const int tid = threadIdx.x;
  const int wv = tid >> 6, l = tid & 63;
  const int lq = l & 31, hi = l >> 5;
  const int b = blockIdx.z, h = blockIdx.y, qt = blockIdx.x;
  const int qrow = (b << 10) + (qt << 7) + (wv << 5) + lq;

  // Q fragments (B-operand): qf[kk] holds d = 16*kk + 8*hi + j, q-row = lq
  const u16* qp = Q + (size_t)qrow * 1024 + h * 64 + hi * 8;
  bf16x8 qf[4];
#pragma unroll
  for (int kk = 0; kk < 4; ++kk) qf[kk] = *(const bf16x8*)(qp + 16 * kk);

  f32x16 acc[2];
#pragma unroll
  for (int d0 = 0; d0 < 2; ++d0)
#pragma unroll
    for (int i = 0; i < 16; ++i) acc[d0][i] = 0.f;
  float m_run = -1e30f, l_run = 0.f;

  // staging sources (thread -> chunk): K chunk(dc=wv, kv=l), V chunk(kvc=wv, d=l)
  const u16* Ksrc = Kb + ((size_t)(b * 2048) + l) * 1024 + h * 64 + wv * 8;
  const u16* Vsrc = Vt + ((size_t)((b * 16 + h) * 64) + l) * 2048 + wv * 8;
  char* ldK = (char*)lK;
  char* ldV = (char*)lV;

#define STAGE_KV(bi, kv0)                                  \
  {                                                        \
    char* dK = ldK + (bi)*8192 + wv * 1024;                \
    char* dV = ldV + (bi)*8192 + wv * 1024;                \
    const u16* ks = Ksrc + (size_t)(kv0) * 1024;           \
    const u16* vs = Vsrc + (kv0);                          \
    GLDS(ks, dK);                                          \
    GLDS(ks + 32, dK + 4096);                              \
    GLDS(vs, dV);                                          \
    GLDS(vs + 32, dV + 4096);                              \
  }

  STAGE_KV(0, 0);
  __syncthreads();
  int buf = 0;

  for (int t = 0; t < 32; ++t) {
    if (t + 1 < 32) STAGE_KV(buf ^ 1, (t + 1) << 6);
    const char* bK = ldK + buf * 8192;
    const char* bV = ldV + buf * 8192;

    // ---- QK^T ----
    f32x16 s[2];
#pragma unroll
    for (int kvh = 0; kvh < 2; ++kvh)
#pragma unroll
      for (int i = 0; i < 16; ++i) s[kvh][i] = 0.f;
    __builtin_amdgcn_s_setprio(1);
#pragma unroll
    for (int kk = 0; kk < 4; ++kk) {
      const char* kbase = bK + (2 * kk + hi) * 1024;
      bf16x8 kf0 = *(const bf16x8*)(kbase + lq * 16);
      bf16x8 kf1 = *(const bf16x8*)(kbase + (32 + lq) * 16);
      s[0] = mfma32(kf0, qf[kk], s[0]);
      s[1] = mfma32(kf1, qf[kk], s[1]);
    }
    __builtin_amdgcn_s_setprio(0);

    // ---- online softmax (exp2 domain), defer-max THR=8 ----
    float tm = s[0][0];
#pragma unroll
    for (int i = 1; i < 16; ++i) tm = fmaxf(tm, s[0][i]);
#pragma unroll
    for (int i = 0; i < 16; ++i) tm = fmaxf(tm, s[1][i]);
    tm = fmaxf(tm, __shfl_xor(tm, 32));
    if (!__all(tm <= m_run + 8.f)) {
      float mnew = fmaxf(m_run, tm);
      float corr = exp2f(m_run - mnew);
      l_run *= corr;
#pragma unroll
      for (int d0 = 0; d0 < 2; ++d0)
#pragma unroll
        for (int i = 0; i < 16; ++i) acc[d0][i] *= corr;
      m_run = mnew;
    }
    float ts = 0.f;
#pragma unroll
    for (int kvh = 0; kvh < 2; ++kvh)
#pragma unroll
      for (int i = 0; i < 16; ++i) {
        float p = exp2f(s[kvh][i] - m_run);
        s[kvh][i] = p;
        ts += p;
      }
    ts += __shfl_xor(ts, 32);
    l_run += ts;

    // ---- pack P -> bf16 pairs: pk[kvh][kp][tt], kv_local = 8*kp + 4*hi + 2*tt ----
    unsigned int pk[2][4][2];
#pragma unroll
    for (int kvh = 0; kvh < 2; ++kvh)
#pragma unroll
      for (int kp = 0; kp < 4; ++kp)
#pragma unroll
        for (int tt = 0; tt < 2; ++tt)
          pk[kvh][kp][tt] = (unsigned)f2bf(s[kvh][4 * kp + 2 * tt]) |
                            ((unsigned)f2bf(s[kvh][4 * kp + 2 * tt + 1]) << 16);

    // ---- PV: per kk build B-frag (P^T) via 2 shfl_xor(32), then 2 mfma ----
#pragma unroll
    for (int kk = 0; kk < 4; ++kk) {
      const int kvh = kk >> 1, kb = kk & 1;
      union { unsigned w[4]; bf16x8 v; } bw;
#pragma unroll
      for (int tt = 0; tt < 2; ++tt) {
        unsigned A0 = pk[kvh][2 * kb][tt];
        unsigned A1 = pk[kvh][2 * kb + 1][tt];
        unsigned S = (unsigned)__shfl_xor((int)(hi ? A0 : A1), 32);
        bw.w[tt] = hi ? S : A0;
        bw.w[2 + tt] = hi ? A1 : S;
      }
      const char* vbase = bV + (2 * kk + hi) * 1024;
      bf16x8 vf0 = *(const bf16x8*)(vbase + lq * 16);
      bf16x8 vf1 = *(const bf16x8*)(vbase + (32 + lq) * 16);
      __builtin_amdgcn_s_setprio(1);
      acc[0] = mfma32(vf0, bw.v, acc[0]);
      acc[1] = mfma32(vf1, bw.v, acc[1]);
      __builtin_amdgcn_s_setprio(0);
    }
    __syncthreads();
    buf ^= 1;
  }
#undef STAGE_KV

  // ---- epilogue: O^T regs -> AO[q][h*64+d], d = 32*d0 + 8*rg + 4*hi + rr ----
  float invl = 1.f / l_run;
#pragma unroll
  for (int d0 = 0; d0 < 2; ++d0)
#pragma unroll
    for (int rg = 0; rg < 4; ++rg) {
      u16x4 o;
#pragma unroll
      for (int rr = 0; rr < 4; ++rr) o[rr] = f2bf(acc[d0][4 * rg + rr] * invl);
      int d = 32 * d0 + 8 * rg + 4 * hi;
      *(u16x4*)(AO + (size_t)qrow * 1024 + h * 64 + d) = o;
    }
}

// ---------------- launch ----------------

extern "C" void kernel_launch(void* const* d_in, const int* in_sizes, int n_in,
                              void* d_out, int out_size, void* d_ws, size_t ws_size,
                              hipStream_t stream) {
  const float* x = (const float*)d_in[0];
  const float* ctx = (const float*)d_in[1];
  const float* Wq = (const float*)d_in[2];
  const float* Wk = (const float*)d_in[3];
  const float* Wv = (const float*)d_in[4];
  const float* Wu = (const float*)d_in[5];
  const float* bu = (const float*)d_in[6];
  const float* qg = (const float*)d_in[7];
  const float* qb = (const float*)d_in[8];
  const float* kg = (const float*)d_in[9];
  const float* kb = (const float*)d_in[10];
  float* out = (float*)d_out;

  char* w = (char*)d_ws;
  u16* XCB = (u16*)(w);                       // 16 MB: xc bf16 [B,T,E]
  u16* WQB = (u16*)(w + ((size_t)16 << 20));  // 2 MB each, contiguous
  u16* WKB = (u16*)(w + ((size_t)18 << 20));
  u16* WVB = (u16*)(w + ((size_t)20 << 20));
  u16* WUB = (u16*)(w + ((size_t)22 << 20));
  u16* QBB = (u16*)(w + ((size_t)24 << 20));  // 8 MB
  u16* KBB = (u16*)(w + ((size_t)32 << 20));  // 16 MB
  u16* VT = (u16*)(w + ((size_t)48 << 20));   // 16 MB
  u16* AO = (u16*)(w + ((size_t)64 << 20));   // 8 MB  (total 72 MB)

  const float invs = 0.17677669529663687f;        // 1024^-0.25
  const float invs_l2e = invs * 1.44269504088896f;  // fold log2(e) into Q for exp2 softmax

  cast_concat<<<2048, 256, 0, stream>>>(x, ctx, XCB);
  cast_w<<<1024, 256, 0, stream>>>(Wq, Wk, Wv, Wu, WQB);

  gemm_bt<0><<<dim3(32, 8), 256, 0, stream>>>(XCB, WQB, QBB, nullptr, qg, qb,
                                              4096, 1024, 1024, 1024, 2048, invs_l2e);
  gemm_bt<0><<<dim3(64, 8), 256, 0, stream>>>(XCB, WKB, KBB, nullptr, kg, kb,
                                              8192, 1024, 1024, 2048, 2048, invs);
  gemm_bt<1><<<dim3(64, 8), 256, 0, stream>>>(XCB, WVB, VT, nullptr, nullptr, nullptr,
                                              8192, 1024, 1024, 2048, 2048, 1.f);

  attn_kernel<<<dim3(8, 16, 4), 256, 0, stream>>>(QBB, KBB, VT, AO);

  gemm_bt<2><<<dim3(32, 8), 256, 0, stream>>>(AO, WUB, nullptr, out, bu, nullptr,
                                              4096, 1024, 1024, 4096, 4096, 1.f);
}

// Round 3
// 297.062 us; speedup vs baseline: 1.0266x; 1.0186x over previous
//
#include <hip/hip_runtime.h>
#include <cstdint>

// ContextualAttention on MI355X (gfx950), all-bf16 MFMA pipeline.
// R3: attn VALU diet (amdgcn exp2, v_cvt_pk_bf16_f32, ILP max/sum trees) +
//     in-block KV-split (8 waves, 512 thr, LDS flash-combine) for 4 waves/SIMD.

typedef unsigned short u16;
typedef __attribute__((ext_vector_type(8))) short bf16x8;
typedef __attribute__((ext_vector_type(4))) float f32x4;
typedef __attribute__((ext_vector_type(16))) float f32x16;
typedef __attribute__((ext_vector_type(4))) unsigned short u16x4;
typedef __attribute__((ext_vector_type(2))) unsigned int u32x2;

#define GLDS(gsrc, ldst)                                                              \
  __builtin_amdgcn_global_load_lds(                                                   \
      (const __attribute__((address_space(1))) unsigned int*)(gsrc),                  \
      (__attribute__((address_space(3))) unsigned int*)(ldst), 16, 0, 0)

__device__ __forceinline__ u16 f2bf(float x) {
  unsigned int u = __float_as_uint(x);
  u += 0x7fffu + ((u >> 16) & 1u);
  return (u16)(u >> 16);
}

// packed f32x2 -> bf16x2 (RNE), single VOP3 (T12 recipe; no builtin on gfx950)
__device__ __forceinline__ unsigned cvt_pk_bf16(float lo, float hi) {
  unsigned r;
  asm("v_cvt_pk_bf16_f32 %0, %1, %2" : "=v"(r) : "v"(lo), "v"(hi));
  return r;
}

__device__ __forceinline__ f32x4 mfma16(bf16x8 a, bf16x8 b, f32x4 c) {
  return __builtin_amdgcn_mfma_f32_16x16x32_bf16(a, b, c, 0, 0, 0);
}
__device__ __forceinline__ f32x16 mfma32(bf16x8 a, bf16x8 b, f32x16 c) {
  return __builtin_amdgcn_mfma_f32_32x32x16_bf16(a, b, c, 0, 0, 0);
}

// ---------------- cast kernels ----------------

__global__ __launch_bounds__(256) void cast_concat(const float* __restrict__ x,
                                                   const float* __restrict__ c,
                                                   u16* __restrict__ o) {
  const int n4 = (8 << 20) / 4;  // B*T*E / 4
  for (int i = blockIdx.x * blockDim.x + threadIdx.x; i < n4; i += gridDim.x * blockDim.x) {
    int elem = i * 4;
    int b = elem >> 21;
    int rem = elem & ((1 << 21) - 1);
    int r = rem >> 10;
    int e = rem & 1023;
    const float* src = (r < 1024) ? (x + ((((size_t)(b << 10)) + r) << 10) + e)
                                  : (c + ((((size_t)(b << 10)) + (r - 1024)) << 10) + e);
    float4 v = *(const float4*)src;
    u16x4 ov;
    ov.x = f2bf(v.x); ov.y = f2bf(v.y); ov.z = f2bf(v.z); ov.w = f2bf(v.w);
    *(u16x4*)(o + elem) = ov;
  }
}

__global__ __launch_bounds__(256) void cast_w(const float* __restrict__ w0,
                                              const float* __restrict__ w1,
                                              const float* __restrict__ w2,
                                              const float* __restrict__ w3,
                                              u16* __restrict__ o) {
  const int n4 = (4 << 20) / 4;
  for (int i = blockIdx.x * blockDim.x + threadIdx.x; i < n4; i += gridDim.x * blockDim.x) {
    int elem = i * 4;
    int sel = elem >> 20;
    int loc = elem & ((1 << 20) - 1);
    const float* s = (sel == 0) ? w0 : (sel == 1) ? w1 : (sel == 2) ? w2 : w3;
    float4 v = *(const float4*)(s + loc);
    u16x4 ov;
    ov.x = f2bf(v.x); ov.y = f2bf(v.y); ov.z = f2bf(v.z); ov.w = f2bf(v.w);
    *(u16x4*)(o + elem) = ov;
  }
}

// ---------------- GEMM: C = A * Bw^T, 128x128 tile, BK=32, 2-phase dbuf ----------------
// EPI 0: per-64-col head LayerNorm(gamma=P0, beta=P1) * oscale -> bf16 Ob row-major
// EPI 1: bf16 transposed write: Ob = Vt[b,h,d,t]
// EPI 2: fp32 + bias(P0) -> Of row-major

template <int EPI>
__global__ __launch_bounds__(256)
void gemm_bt(const u16* __restrict__ A, const u16* __restrict__ Bw,
             u16* __restrict__ Ob, float* __restrict__ Of,
             const float* __restrict__ P0, const float* __restrict__ P1,
             int M, int N, int K, int rpbo, int rpbi, float oscale) {
  __shared__ alignas(16) u16 lA[2][128 * 32];
  __shared__ alignas(16) u16 lB[2][128 * 32];
  const int tid = threadIdx.x;
  const int wv = tid >> 6, l = tid & 63, g = l >> 4, c16 = l & 15;
  const int wr = wv >> 1, wc = wv & 1;
  const int m0 = blockIdx.x * 128, n0 = blockIdx.y * 128;
  const int arow0 = (m0 / rpbo) * rpbi + (m0 % rpbo);

  f32x4 acc[4][4];
  const f32x4 z4 = {0.f, 0.f, 0.f, 0.f};
#pragma unroll
  for (int i = 0; i < 4; ++i)
#pragma unroll
    for (int j = 0; j < 4; ++j) acc[i][j] = z4;

  // staging: 16B chunks, linear LDS dest, XOR-swizzled global source
  const int srow = tid >> 2;
  const int scA = (tid & 3) ^ (srow & 3);
  const u16* aSrc = A + (size_t)(arow0 + srow) * K + scA * 8;
  const u16* bSrc = Bw + (size_t)(n0 + srow) * K + scA * 8;
  char* ldA = (char*)lA;
  char* ldB = (char*)lB;
  const int lof = wv * 1024;

  const int ksteps = K >> 5;
#define STAGE_G(bi, kof)                                   \
  {                                                        \
    char* dA = ldA + (bi)*8192 + lof;                      \
    char* dB = ldB + (bi)*8192 + lof;                      \
    GLDS(aSrc + (kof), dA);                                \
    GLDS(aSrc + (size_t)64 * K + (kof), dA + 4096);        \
    GLDS(bSrc + (kof), dB);                                \
    GLDS(bSrc + (size_t)64 * K + (kof), dB + 4096);        \
  }

  STAGE_G(0, 0);
  __syncthreads();
  int buf = 0;
  for (int kt = 0; kt < ksteps; ++kt) {
    if (kt + 1 < ksteps) STAGE_G(buf ^ 1, (kt + 1) << 5);
    const char* bA = ldA + buf * 8192;
    const char* bB = ldB + buf * 8192;
    bf16x8 af[4], bfr[4];
#pragma unroll
    for (int mi = 0; mi < 4; ++mi) {
      int row = wr * 64 + mi * 16 + c16;
      af[mi] = *(const bf16x8*)(bA + row * 64 + ((g * 16) ^ ((row & 3) << 4)));
    }
#pragma unroll
    for (int ni = 0; ni < 4; ++ni) {
      int row = wc * 64 + ni * 16 + c16;
      bfr[ni] = *(const bf16x8*)(bB + row * 64 + ((g * 16) ^ ((row & 3) << 4)));
    }
#pragma unroll
    for (int mi = 0; mi < 4; ++mi)
#pragma unroll
      for (int ni = 0; ni < 4; ++ni)
        acc[mi][ni] = mfma16(af[mi], bfr[ni], acc[mi][ni]);
    __syncthreads();
    buf ^= 1;
  }
#undef STAGE_G

  // ---- epilogues ----  C layout: col = l&15, row = (l>>4)*4 + reg
  if constexpr (EPI == 2) {
#pragma unroll
    for (int ni = 0; ni < 4; ++ni) {
      int col = n0 + wc * 64 + ni * 16 + c16;
      float bv = P0[col];
#pragma unroll
      for (int mi = 0; mi < 4; ++mi) {
        int row = m0 + wr * 64 + mi * 16 + g * 4;
        float* dst = Of + (size_t)row * N + col;
#pragma unroll
        for (int r = 0; r < 4; ++r) dst[(size_t)r * N] = acc[mi][ni][r] + bv;
      }
    }
  } else if constexpr (EPI == 1) {
#pragma unroll
    for (int ni = 0; ni < 4; ++ni) {
      int col = n0 + wc * 64 + ni * 16 + c16;
      int hh = col >> 6, dd = col & 63;
#pragma unroll
      for (int mi = 0; mi < 4; ++mi) {
        int m = m0 + wr * 64 + mi * 16 + g * 4;
        int bb = m >> 11, tt = m & 2047;
        u16x4 o;
#pragma unroll
        for (int r = 0; r < 4; ++r) o[r] = f2bf(acc[mi][ni][r]);
        *(u16x4*)(Ob + ((size_t)((bb * 16 + hh) * 64 + dd)) * 2048 + tt) = o;
      }
    }
  } else {
#pragma unroll
    for (int mi = 0; mi < 4; ++mi) {
      float sum[4], sq[4];
#pragma unroll
      for (int r = 0; r < 4; ++r) {
        float s = 0.f, q = 0.f;
#pragma unroll
        for (int ni = 0; ni < 4; ++ni) {
          float v = acc[mi][ni][r];
          s += v;
          q += v * v;
        }
#pragma unroll
        for (int msk = 1; msk < 16; msk <<= 1) {
          s += __shfl_xor(s, msk);
          q += __shfl_xor(q, msk);
        }
        sum[r] = s;
        sq[r] = q;
      }
#pragma unroll
      for (int ni = 0; ni < 4; ++ni) {
        int dloc = ni * 16 + c16;
        int colg = n0 + wc * 64 + ni * 16 + c16;
        float gv = P0[dloc], bv = P1[dloc];
#pragma unroll
        for (int r = 0; r < 4; ++r) {
          float mean = sum[r] * (1.f / 64.f);
          float var = sq[r] * (1.f / 64.f) - mean * mean;
          float y = (acc[mi][ni][r] - mean) * rsqrtf(var + 1e-5f) * gv + bv;
          int row = m0 + wr * 64 + mi * 16 + g * 4 + r;
          Ob[(size_t)row * N + colg] = f2bf(y * oscale);
        }
      }
    }
  }
}

// ---------------- flash attention, 32x32 MFMA, in-block KV-split ----------------
// block = 512 thr = 8 waves over one (b,h,128 q-rows).
// Wave wv: wq = wv&3 owns q-rows [wq*32..+32); kvh2 = wv>>2 selects KV-tile parity:
// half 0 computes even 64-KV tiles, half 1 odd tiles. At the end the two partials
// (m, l, unnormalized O) are merged exactly through LDS.
// LDS column-chunk layout (conflict-free b128, linear global_load_lds):
//   K: addr = dchunk*1024 + kv*16   ; V: addr = kvchunk*1024 + d*16
// QK^T swapped: s = mfma32(A=K, B=Q) -> S^T: col q=l&31, row kv=(r&3)+8*(r>>2)+4*hi.
// Softmax in exp2-domain (log2e folded into Q's LN epilogue scale), defer-max THR=8.

__global__ __launch_bounds__(512, 4)
void attn_kernel(const u16* __restrict__ Q, const u16* __restrict__ Kb,
                 const u16* __restrict__ Vt, u16* __restrict__ AO) {
  __shared__ alignas(16) u16 lK[2][2][4096];  // [kvh2][buf]
  __shared__ alignas(16) u16 lV[2][2][4096];
  __shared__ float cmb[4][64][34];  // per upper-wave partial: acc(32) + m + l
  const int tid = threadIdx.x;
  const int wv = tid >> 6, l = tid & 63;
  const int w4 = wv & 3, kvh2 = wv >> 2;
  const int lq = l & 31, hi = l >> 5;
  const int b = blockIdx.z, h = blockIdx.y, qt = blockIdx.x;
  const int qrow = (b << 10) + (qt << 7) + (w4 << 5) + lq;

  // Q fragments (B-operand): qf[kk] holds d = 16*kk + 8*hi + j, q-row = lq
  const u16* qp = Q + (size_t)qrow * 1024 + h * 64 + hi * 8;
  bf16x8 qf[4];
#pragma unroll
  for (int kk = 0; kk < 4; ++kk) qf[kk] = *(const bf16x8*)(qp + 16 * kk);

  f32x16 acc[2];
#pragma unroll
  for (int d0 = 0; d0 < 2; ++d0)
#pragma unroll
    for (int i = 0; i < 16; ++i) acc[d0][i] = 0.f;
  float m_run = -1e30f, l_run = 0.f;

  // staging sources: K chunk(dc=w4, kv=l), V chunk(kvc=w4, d=l); each half its own tiles
  const u16* Ksrc = Kb + ((size_t)(b * 2048) + l) * 1024 + h * 64 + w4 * 8;
  const u16* Vsrc = Vt + ((size_t)((b * 16 + h) * 64) + l) * 2048 + w4 * 8;

#define STAGE_KV(bi, it)                                    \
  {                                                         \
    const int kv0 = ((it) << 7) + (kvh2 << 6);              \
    char* dK = (char*)lK[kvh2][bi] + w4 * 1024;             \
    char* dV = (char*)lV[kvh2][bi] + w4 * 1024;             \
    const u16* ks = Ksrc + (size_t)kv0 * 1024;              \
    const u16* vs = Vsrc + kv0;                             \
    GLDS(ks, dK);                                           \
    GLDS(ks + 32, dK + 4096);                               \
    GLDS(vs, dV);                                           \
    GLDS(vs + 32, dV + 4096);                               \
  }

  STAGE_KV(0, 0);
  __syncthreads();
  int buf = 0;

  for (int it = 0; it < 16; ++it) {
    if (it + 1 < 16) STAGE_KV(buf ^ 1, it + 1);
    const char* bK = (const char*)lK[kvh2][buf];
    const char* bV = (const char*)lV[kvh2][buf];

    // ---- QK^T ----
    f32x16 s[2];
#pragma unroll
    for (int kvh = 0; kvh < 2; ++kvh)
#pragma unroll
      for (int i = 0; i < 16; ++i) s[kvh][i] = 0.f;
    __builtin_amdgcn_s_setprio(1);
#pragma unroll
    for (int kk = 0; kk < 4; ++kk) {
      const char* kbase = bK + (2 * kk + hi) * 1024;
      bf16x8 kf0 = *(const bf16x8*)(kbase + lq * 16);
      bf16x8 kf1 = *(const bf16x8*)(kbase + (32 + lq) * 16);
      s[0] = mfma32(kf0, qf[kk], s[0]);
      s[1] = mfma32(kf1, qf[kk], s[1]);
    }
    __builtin_amdgcn_s_setprio(0);

    // ---- online softmax (exp2 domain), defer-max THR=8, 4-way-ILP trees ----
    float tm0 = fmaxf(s[0][0], s[1][0]), tm1 = fmaxf(s[0][1], s[1][1]);
    float tm2 = fmaxf(s[0][2], s[1][2]), tm3 = fmaxf(s[0][3], s[1][3]);
#pragma unroll
    for (int i = 4; i < 16; i += 4) {
      tm0 = fmaxf(tm0, fmaxf(s[0][i], s[1][i]));
      tm1 = fmaxf(tm1, fmaxf(s[0][i + 1], s[1][i + 1]));
      tm2 = fmaxf(tm2, fmaxf(s[0][i + 2], s[1][i + 2]));
      tm3 = fmaxf(tm3, fmaxf(s[0][i + 3], s[1][i + 3]));
    }
    float tm = fmaxf(fmaxf(tm0, tm1), fmaxf(tm2, tm3));
    tm = fmaxf(tm, __shfl_xor(tm, 32));
    if (!__all(tm <= m_run + 8.f)) {
      float mnew = fmaxf(m_run, tm);
      float corr = __builtin_amdgcn_exp2f(m_run - mnew);
      l_run *= corr;
#pragma unroll
      for (int d0 = 0; d0 < 2; ++d0)
#pragma unroll
        for (int i = 0; i < 16; ++i) acc[d0][i] *= corr;
      m_run = mnew;
    }
    float ts0 = 0.f, ts1 = 0.f, ts2 = 0.f, ts3 = 0.f;
#pragma unroll
    for (int kvh = 0; kvh < 2; ++kvh)
#pragma unroll
      for (int i = 0; i < 16; i += 4) {
        float p0 = __builtin_amdgcn_exp2f(s[kvh][i] - m_run);
        float p1 = __builtin_amdgcn_exp2f(s[kvh][i + 1] - m_run);
        float p2 = __builtin_amdgcn_exp2f(s[kvh][i + 2] - m_run);
        float p3 = __builtin_amdgcn_exp2f(s[kvh][i + 3] - m_run);
        s[kvh][i] = p0; s[kvh][i + 1] = p1; s[kvh][i + 2] = p2; s[kvh][i + 3] = p3;
        ts0 += p0; ts1 += p1; ts2 += p2; ts3 += p3;
      }
    float ts = (ts0 + ts1) + (ts2 + ts3);
    ts += __shfl_xor(ts, 32);
    l_run += ts;

    // ---- pack P -> bf16 pairs (1 VOP3 each): pk[kvh][kp][tt], kv_local = 8*kp+4*hi+2*tt
    unsigned int pk[2][4][2];
#pragma unroll
    for (int kvh = 0; kvh < 2; ++kvh)
#pragma unroll
      for (int kp = 0; kp < 4; ++kp)
#pragma unroll
        for (int tt = 0; tt < 2; ++tt)
          pk[kvh][kp][tt] = cvt_pk_bf16(s[kvh][4 * kp + 2 * tt], s[kvh][4 * kp + 2 * tt + 1]);

    // ---- PV: per kk build B-frag (P^T) via shfl_xor(32), then 2 mfma ----
#pragma unroll
    for (int kk = 0; kk < 4; ++kk) {
      const int kvh = kk >> 1, kb = kk & 1;
      union { unsigned w[4]; bf16x8 v; } bw;
#pragma unroll
      for (int tt = 0; tt < 2; ++tt) {
        unsigned A0 = pk[kvh][2 * kb][tt];
        unsigned A1 = pk[kvh][2 * kb + 1][tt];
        unsigned S = (unsigned)__shfl_xor((int)(hi ? A0 : A1), 32);
        bw.w[tt] = hi ? S : A0;
        bw.w[2 + tt] = hi ? A1 : S;
      }
      const char* vbase = bV + (2 * kk + hi) * 1024;
      bf16x8 vf0 = *(const bf16x8*)(vbase + lq * 16);
      bf16x8 vf1 = *(const bf16x8*)(vbase + (32 + lq) * 16);
      __builtin_amdgcn_s_setprio(1);
      acc[0] = mfma32(vf0, bw.v, acc[0]);
      acc[1] = mfma32(vf1, bw.v, acc[1]);
      __builtin_amdgcn_s_setprio(0);
    }
    __syncthreads();
    buf ^= 1;
  }
#undef STAGE_KV

  // ---- merge the two KV halves (exact flash combine), then write ----
  if (wv >= 4) {
    float* cp = cmb[w4][l];
#pragma unroll
    for (int d0 = 0; d0 < 2; ++d0)
#pragma unroll
      for (int i = 0; i < 16; ++i) cp[d0 * 16 + i] = acc[d0][i];
    cp[32] = m_run;
    cp[33] = l_run;
  }
  __syncthreads();
  if (wv < 4) {
    const float* cp = cmb[w4][l];
    float m1 = cp[32], l1 = cp[33];
    float mm = fmaxf(m_run, m1);
    float c0 = __builtin_amdgcn_exp2f(m_run - mm);
    float c1 = __builtin_amdgcn_exp2f(m1 - mm);
    float invl = 1.f / (l_run * c0 + l1 * c1);
    float s0 = c0 * invl, s1 = c1 * invl;
    // O^T regs -> AO[q][h*64+d], d = 32*d0 + 8*rg + 4*hi + rr
#pragma unroll
    for (int d0 = 0; d0 < 2; ++d0)
#pragma unroll
      for (int rg = 0; rg < 4; ++rg) {
        float v0 = acc[d0][4 * rg + 0] * s0 + cp[d0 * 16 + 4 * rg + 0] * s1;
        float v1 = acc[d0][4 * rg + 1] * s0 + cp[d0 * 16 + 4 * rg + 1] * s1;
        float v2 = acc[d0][4 * rg + 2] * s0 + cp[d0 * 16 + 4 * rg + 2] * s1;
        float v3 = acc[d0][4 * rg + 3] * s0 + cp[d0 * 16 + 4 * rg + 3] * s1;
        u32x2 o;
        o.x = cvt_pk_bf16(v0, v1);
        o.y = cvt_pk_bf16(v2, v3);
        int d = 32 * d0 + 8 * rg + 4 * hi;
        *(u32x2*)(AO + (size_t)qrow * 1024 + h * 64 + d) = o;
      }
  }
}

// ---------------- launch ----------------

extern "C" void kernel_launch(void* const* d_in, const int* in_sizes, int n_in,
                              void* d_out, int out_size, void* d_ws, size_t ws_size,
                              hipStream_t stream) {
  const float* x = (const float*)d_in[0];
  const float* ctx = (const float*)d_in[1];
  const float* Wq = (const float*)d_in[2];
  const float* Wk = (const float*)d_in[3];
  const float* Wv = (const float*)d_in[4];
  const float* Wu = (const float*)d_in[5];
  const float* bu = (const float*)d_in[6];
  const float* qg = (const float*)d_in[7];
  const float* qb = (const float*)d_in[8];
  const float* kg = (const float*)d_in[9];
  const float* kb = (const float*)d_in[10];
  float* out = (float*)d_out;

  char* w = (char*)d_ws;
  u16* XCB = (u16*)(w);                       // 16 MB: xc bf16 [B,T,E]
  u16* WQB = (u16*)(w + ((size_t)16 << 20));  // 2 MB each, contiguous
  u16* WKB = (u16*)(w + ((size_t)18 << 20));
  u16* WVB = (u16*)(w + ((size_t)20 << 20));
  u16* WUB = (u16*)(w + ((size_t)22 << 20));
  u16* QBB = (u16*)(w + ((size_t)24 << 20));  // 8 MB
  u16* KBB = (u16*)(w + ((size_t)32 << 20));  // 16 MB
  u16* VT = (u16*)(w + ((size_t)48 << 20));   // 16 MB
  u16* AO = (u16*)(w + ((size_t)64 << 20));   // 8 MB  (total 72 MB)

  const float invs = 0.17677669529663687f;          // 1024^-0.25
  const float invs_l2e = invs * 1.44269504088896f;  // fold log2(e) into Q for exp2 softmax

  cast_concat<<<2048, 256, 0, stream>>>(x, ctx, XCB);
  cast_w<<<1024, 256, 0, stream>>>(Wq, Wk, Wv, Wu, WQB);

  gemm_bt<0><<<dim3(32, 8), 256, 0, stream>>>(XCB, WQB, QBB, nullptr, qg, qb,
                                              4096, 1024, 1024, 1024, 2048, invs_l2e);
  gemm_bt<0><<<dim3(64, 8), 256, 0, stream>>>(XCB, WKB, KBB, nullptr, kg, kb,
                                              8192, 1024, 1024, 2048, 2048, invs);
  gemm_bt<1><<<dim3(64, 8), 256, 0, stream>>>(XCB, WVB, VT, nullptr, nullptr, nullptr,
                                              8192, 1024, 1024, 2048, 2048, 1.f);

  attn_kernel<<<dim3(8, 16, 4), 512, 0, stream>>>(QBB, KBB, VT, AO);

  gemm_bt<2><<<dim3(32, 8), 256, 0, stream>>>(AO, WUB, nullptr, out, bu, nullptr,
                                              4096, 1024, 1024, 4096, 4096, 1.f);
}

// Round 4
// 276.550 us; speedup vs baseline: 1.1027x; 1.0742x over previous
//
#include <hip/hip_runtime.h>
#include <cstdint>

// ContextualAttention on MI355X (gfx950), all-bf16 MFMA pipeline.
// R4: attn LDS union (cmb aliases K/V tiles) -> 64 KB -> 2 blocks/CU;
//     merged QKV GEMM (one 1280-block dispatch); 64x128-tile final GEMM.

typedef unsigned short u16;
typedef __attribute__((ext_vector_type(8))) short bf16x8;
typedef __attribute__((ext_vector_type(4))) float f32x4;
typedef __attribute__((ext_vector_type(16))) float f32x16;
typedef __attribute__((ext_vector_type(4))) unsigned short u16x4;
typedef __attribute__((ext_vector_type(2))) unsigned int u32x2;

#define GLDS(gsrc, ldst)                                                              \
  __builtin_amdgcn_global_load_lds(                                                   \
      (const __attribute__((address_space(1))) unsigned int*)(gsrc),                  \
      (__attribute__((address_space(3))) unsigned int*)(ldst), 16, 0, 0)

__device__ __forceinline__ u16 f2bf(float x) {
  unsigned int u = __float_as_uint(x);
  u += 0x7fffu + ((u >> 16) & 1u);
  return (u16)(u >> 16);
}

// packed f32x2 -> bf16x2 (RNE), single VOP3 (T12 recipe; no builtin on gfx950)
__device__ __forceinline__ unsigned cvt_pk_bf16(float lo, float hi) {
  unsigned r;
  asm("v_cvt_pk_bf16_f32 %0, %1, %2" : "=v"(r) : "v"(lo), "v"(hi));
  return r;
}

__device__ __forceinline__ f32x4 mfma16(bf16x8 a, bf16x8 b, f32x4 c) {
  return __builtin_amdgcn_mfma_f32_16x16x32_bf16(a, b, c, 0, 0, 0);
}
__device__ __forceinline__ f32x16 mfma32(bf16x8 a, bf16x8 b, f32x16 c) {
  return __builtin_amdgcn_mfma_f32_32x32x16_bf16(a, b, c, 0, 0, 0);
}

// ---------------- cast kernels ----------------

__global__ __launch_bounds__(256) void cast_concat(const float* __restrict__ x,
                                                   const float* __restrict__ c,
                                                   u16* __restrict__ o) {
  const int n4 = (8 << 20) / 4;  // B*T*E / 4
  for (int i = blockIdx.x * blockDim.x + threadIdx.x; i < n4; i += gridDim.x * blockDim.x) {
    int elem = i * 4;
    int b = elem >> 21;
    int rem = elem & ((1 << 21) - 1);
    int r = rem >> 10;
    int e = rem & 1023;
    const float* src = (r < 1024) ? (x + ((((size_t)(b << 10)) + r) << 10) + e)
                                  : (c + ((((size_t)(b << 10)) + (r - 1024)) << 10) + e);
    float4 v = *(const float4*)src;
    u16x4 ov;
    ov.x = f2bf(v.x); ov.y = f2bf(v.y); ov.z = f2bf(v.z); ov.w = f2bf(v.w);
    *(u16x4*)(o + elem) = ov;
  }
}

__global__ __launch_bounds__(256) void cast_w(const float* __restrict__ w0,
                                              const float* __restrict__ w1,
                                              const float* __restrict__ w2,
                                              const float* __restrict__ w3,
                                              u16* __restrict__ o) {
  const int n4 = (4 << 20) / 4;
  for (int i = blockIdx.x * blockDim.x + threadIdx.x; i < n4; i += gridDim.x * blockDim.x) {
    int elem = i * 4;
    int sel = elem >> 20;
    int loc = elem & ((1 << 20) - 1);
    const float* s = (sel == 0) ? w0 : (sel == 1) ? w1 : (sel == 2) ? w2 : w3;
    float4 v = *(const float4*)(s + loc);
    u16x4 ov;
    ov.x = f2bf(v.x); ov.y = f2bf(v.y); ov.z = f2bf(v.z); ov.w = f2bf(v.w);
    *(u16x4*)(o + elem) = ov;
  }
}

// ---------------- merged QKV GEMM: 128x128 tile, BK=32, 2-phase dbuf ----------------
// grid (64, 24). ny>>3 selects: 0=Q (LN epi, compacted rows), 1=K (LN epi),
// 2=V (transposed bf16 write). Q blocks over context rows exit immediately.

__global__ __launch_bounds__(256)
void gemm_qkv(const u16* __restrict__ XCB, const u16* __restrict__ Wall,
              u16* __restrict__ QBB, u16* __restrict__ KBB, u16* __restrict__ VT,
              const float* __restrict__ qg, const float* __restrict__ qb,
              const float* __restrict__ kg, const float* __restrict__ kb,
              float sQ, float sK) {
  const int ny = blockIdx.y;
  const int which = ny >> 3;
  const int m0 = blockIdx.x << 7;
  if (which == 0 && (m0 & 2047) >= 1024) return;  // Q only from x rows
  const int n0 = (ny & 7) << 7;
  const u16* Bw = Wall + ((size_t)which << 20);
  const int K = 1024, N = 1024;

  __shared__ alignas(16) u16 lA[2][128 * 32];
  __shared__ alignas(16) u16 lB[2][128 * 32];
  const int tid = threadIdx.x;
  const int wv = tid >> 6, l = tid & 63, g = l >> 4, c16 = l & 15;
  const int wr = wv >> 1, wc = wv & 1;

  f32x4 acc[4][4];
  const f32x4 z4 = {0.f, 0.f, 0.f, 0.f};
#pragma unroll
  for (int i = 0; i < 4; ++i)
#pragma unroll
    for (int j = 0; j < 4; ++j) acc[i][j] = z4;

  const int srow = tid >> 2;
  const int scA = (tid & 3) ^ (srow & 3);
  const u16* aSrc = XCB + (size_t)(m0 + srow) * K + scA * 8;
  const u16* bSrc = Bw + (size_t)(n0 + srow) * K + scA * 8;
  char* ldA = (char*)lA;
  char* ldB = (char*)lB;
  const int lof = wv * 1024;

#define STAGE_G(bi, kof)                                   \
  {                                                        \
    char* dA = ldA + (bi)*8192 + lof;                      \
    char* dB = ldB + (bi)*8192 + lof;                      \
    GLDS(aSrc + (kof), dA);                                \
    GLDS(aSrc + (size_t)64 * K + (kof), dA + 4096);        \
    GLDS(bSrc + (kof), dB);                                \
    GLDS(bSrc + (size_t)64 * K + (kof), dB + 4096);        \
  }

  STAGE_G(0, 0);
  __syncthreads();
  int buf = 0;
  for (int kt = 0; kt < 32; ++kt) {
    if (kt + 1 < 32) STAGE_G(buf ^ 1, (kt + 1) << 5);
    const char* bA = ldA + buf * 8192;
    const char* bB = ldB + buf * 8192;
    bf16x8 af[4], bfr[4];
#pragma unroll
    for (int mi = 0; mi < 4; ++mi) {
      int row = wr * 64 + mi * 16 + c16;
      af[mi] = *(const bf16x8*)(bA + row * 64 + ((g * 16) ^ ((row & 3) << 4)));
    }
#pragma unroll
    for (int ni = 0; ni < 4; ++ni) {
      int row = wc * 64 + ni * 16 + c16;
      bfr[ni] = *(const bf16x8*)(bB + row * 64 + ((g * 16) ^ ((row & 3) << 4)));
    }
    __builtin_amdgcn_s_setprio(1);
#pragma unroll
    for (int mi = 0; mi < 4; ++mi)
#pragma unroll
      for (int ni = 0; ni < 4; ++ni)
        acc[mi][ni] = mfma16(af[mi], bfr[ni], acc[mi][ni]);
    __builtin_amdgcn_s_setprio(0);
    __syncthreads();
    buf ^= 1;
  }
#undef STAGE_G

  // ---- epilogues ----  C layout: col = l&15, row = (l>>4)*4 + reg
  if (which == 2) {
    // Vt[((b*16+h)*64+d)*2048 + t]; m = b*2048+t, col = h*64+d
#pragma unroll
    for (int ni = 0; ni < 4; ++ni) {
      int col = n0 + wc * 64 + ni * 16 + c16;
      int hh = col >> 6, dd = col & 63;
#pragma unroll
      for (int mi = 0; mi < 4; ++mi) {
        int m = m0 + wr * 64 + mi * 16 + g * 4;
        int bb = m >> 11, tt = m & 2047;
        u16x4 o;
#pragma unroll
        for (int r = 0; r < 4; ++r) o[r] = f2bf(acc[mi][ni][r]);
        *(u16x4*)(VT + ((size_t)((bb * 16 + hh) * 64 + dd)) * 2048 + tt) = o;
      }
    }
  } else {
    const float* G = which ? kg : qg;
    const float* Bt = which ? kb : qb;
    const float osc = which ? sK : sQ;
    u16* Ob = which ? KBB : QBB;
#pragma unroll
    for (int mi = 0; mi < 4; ++mi) {
      float sum[4], sq[4];
#pragma unroll
      for (int r = 0; r < 4; ++r) {
        float s = 0.f, q = 0.f;
#pragma unroll
        for (int ni = 0; ni < 4; ++ni) {
          float v = acc[mi][ni][r];
          s += v;
          q += v * v;
        }
#pragma unroll
        for (int msk = 1; msk < 16; msk <<= 1) {
          s += __shfl_xor(s, msk);
          q += __shfl_xor(q, msk);
        }
        sum[r] = s;
        sq[r] = q;
      }
#pragma unroll
      for (int ni = 0; ni < 4; ++ni) {
        int dloc = ni * 16 + c16;  // head-local (n0, wc*64 are 64-aligned)
        int colg = n0 + wc * 64 + ni * 16 + c16;
        float gv = G[dloc], bv = Bt[dloc];
#pragma unroll
        for (int r = 0; r < 4; ++r) {
          float mean = sum[r] * (1.f / 64.f);
          float var = sq[r] * (1.f / 64.f) - mean * mean;
          float y = (acc[mi][ni][r] - mean) * rsqrtf(var + 1e-5f) * gv + bv;
          int row = m0 + wr * 64 + mi * 16 + g * 4 + r;
          int orow = which ? row : (((row >> 11) << 10) | (row & 1023));
          Ob[(size_t)orow * N + colg] = f2bf(y * osc);
        }
      }
    }
  }
}

// ---------------- final GEMM: out = AO * Wu^T + bu, 64x128 tile ----------------

__global__ __launch_bounds__(256)
void gemm_u64(const u16* __restrict__ A, const u16* __restrict__ Bw,
              float* __restrict__ Of, const float* __restrict__ bias) {
  const int K = 1024, N = 1024;
  __shared__ alignas(16) u16 lA[2][64 * 32];
  __shared__ alignas(16) u16 lB[2][128 * 32];
  const int tid = threadIdx.x;
  const int wv = tid >> 6, l = tid & 63, g = l >> 4, c16 = l & 15;
  const int wr = wv >> 1, wc = wv & 1;
  const int m0 = blockIdx.x << 6, n0 = blockIdx.y << 7;

  f32x4 acc[2][4];
  const f32x4 z4 = {0.f, 0.f, 0.f, 0.f};
#pragma unroll
  for (int i = 0; i < 2; ++i)
#pragma unroll
    for (int j = 0; j < 4; ++j) acc[i][j] = z4;

  const int srow = tid >> 2;
  const int sc = (tid & 3) ^ (srow & 3);
  const u16* aSrc = A + (size_t)(m0 + srow) * K + sc * 8;  // srow < 64
  const u16* bSrc = Bw + (size_t)(n0 + srow) * K + sc * 8;
  char* ldA = (char*)lA;
  char* ldB = (char*)lB;
  const int lof = wv * 1024;

#define STAGE_U(bi, kof)                                   \
  {                                                        \
    char* dA = ldA + (bi)*4096 + lof;                      \
    char* dB = ldB + (bi)*8192 + lof;                      \
    GLDS(aSrc + (kof), dA);                                \
    GLDS(bSrc + (kof), dB);                                \
    GLDS(bSrc + (size_t)64 * K + (kof), dB + 4096);        \
  }

  STAGE_U(0, 0);
  __syncthreads();
  int buf = 0;
  for (int kt = 0; kt < 32; ++kt) {
    if (kt + 1 < 32) STAGE_U(buf ^ 1, (kt + 1) << 5);
    const char* bA = ldA + buf * 4096;
    const char* bB = ldB + buf * 8192;
    bf16x8 af[2], bfr[4];
#pragma unroll
    for (int mi = 0; mi < 2; ++mi) {
      int row = wr * 32 + mi * 16 + c16;
      af[mi] = *(const bf16x8*)(bA + row * 64 + ((g * 16) ^ ((row & 3) << 4)));
    }
#pragma unroll
    for (int ni = 0; ni < 4; ++ni) {
      int row = wc * 64 + ni * 16 + c16;
      bfr[ni] = *(const bf16x8*)(bB + row * 64 + ((g * 16) ^ ((row & 3) << 4)));
    }
    __builtin_amdgcn_s_setprio(1);
#pragma unroll
    for (int mi = 0; mi < 2; ++mi)
#pragma unroll
      for (int ni = 0; ni < 4; ++ni)
        acc[mi][ni] = mfma16(af[mi], bfr[ni], acc[mi][ni]);
    __builtin_amdgcn_s_setprio(0);
    __syncthreads();
    buf ^= 1;
  }
#undef STAGE_U

#pragma unroll
  for (int ni = 0; ni < 4; ++ni) {
    int col = n0 + wc * 64 + ni * 16 + c16;
    float bv = bias[col];
#pragma unroll
    for (int mi = 0; mi < 2; ++mi) {
      int row = m0 + wr * 32 + mi * 16 + g * 4;
      float* dst = Of + (size_t)row * N + col;
#pragma unroll
      for (int r = 0; r < 4; ++r) dst[(size_t)r * N] = acc[mi][ni][r] + bv;
    }
  }
}

// ---------------- flash attention, 32x32 MFMA, in-block KV-split ----------------
// block = 512 thr = 8 waves over one (b,h,128 q-rows).
// Wave wv: w4 = wv&3 owns q-rows [w4*32..+32); kvh2 = wv>>2 selects KV-tile parity.
// Final combine buffer ALIASES the K/V tiles (union) -> LDS = 64 KB -> 2 blocks/CU.

__global__ __launch_bounds__(512, 4)
void attn_kernel(const u16* __restrict__ Q, const u16* __restrict__ Kb,
                 const u16* __restrict__ Vt, u16* __restrict__ AO) {
  __shared__ union alignas(16) {
    struct { u16 K[2][2][4096]; u16 V[2][2][4096]; } kv;  // [kvh2][buf], 64 KB
    float cmb[4][64][34];                                 // used only after the loop
  } sm;
  const int tid = threadIdx.x;
  const int wv = tid >> 6, l = tid & 63;
  const int w4 = wv & 3, kvh2 = wv >> 2;
  const int lq = l & 31, hi = l >> 5;
  const int b = blockIdx.z, h = blockIdx.y, qt = blockIdx.x;
  const int qrow = (b << 10) + (qt << 7) + (w4 << 5) + lq;

  // Q fragments (B-operand): qf[kk] holds d = 16*kk + 8*hi + j, q-row = lq
  const u16* qp = Q + (size_t)qrow * 1024 + h * 64 + hi * 8;
  bf16x8 qf[4];
#pragma unroll
  for (int kk = 0; kk < 4; ++kk) qf[kk] = *(const bf16x8*)(qp + 16 * kk);

  f32x16 acc[2];
#pragma unroll
  for (int d0 = 0; d0 < 2; ++d0)
#pragma unroll
    for (int i = 0; i < 16; ++i) acc[d0][i] = 0.f;
  float m_run = -1e30f, l_run = 0.f;

  // staging sources: K chunk(dc=w4, kv=l), V chunk(kvc=w4, d=l); each parity its own tiles
  const u16* Ksrc = Kb + ((size_t)(b * 2048) + l) * 1024 + h * 64 + w4 * 8;
  const u16* Vsrc = Vt + ((size_t)((b * 16 + h) * 64) + l) * 2048 + w4 * 8;

#define STAGE_KV(bi, it)                                    \
  {                                                         \
    const int kv0 = ((it) << 7) + (kvh2 << 6);              \
    char* dK = (char*)sm.kv.K[kvh2][bi] + w4 * 1024;        \
    char* dV = (char*)sm.kv.V[kvh2][bi] + w4 * 1024;        \
    const u16* ks = Ksrc + (size_t)kv0 * 1024;              \
    const u16* vs = Vsrc + kv0;                             \
    GLDS(ks, dK);                                           \
    GLDS(ks + 32, dK + 4096);                               \
    GLDS(vs, dV);                                           \
    GLDS(vs + 32, dV + 4096);                               \
  }

  STAGE_KV(0, 0);
  __syncthreads();
  int buf = 0;

  for (int it = 0; it < 16; ++it) {
    if (it + 1 < 16) STAGE_KV(buf ^ 1, it + 1);
    const char* bK = (const char*)sm.kv.K[kvh2][buf];
    const char* bV = (const char*)sm.kv.V[kvh2][buf];

    // ---- QK^T ----
    f32x16 s[2];
#pragma unroll
    for (int kvh = 0; kvh < 2; ++kvh)
#pragma unroll
      for (int i = 0; i < 16; ++i) s[kvh][i] = 0.f;
    __builtin_amdgcn_s_setprio(1);
#pragma unroll
    for (int kk = 0; kk < 4; ++kk) {
      const char* kbase = bK + (2 * kk + hi) * 1024;
      bf16x8 kf0 = *(const bf16x8*)(kbase + lq * 16);
      bf16x8 kf1 = *(const bf16x8*)(kbase + (32 + lq) * 16);
      s[0] = mfma32(kf0, qf[kk], s[0]);
      s[1] = mfma32(kf1, qf[kk], s[1]);
    }
    __builtin_amdgcn_s_setprio(0);

    // ---- online softmax (exp2 domain), defer-max THR=8, 4-way-ILP trees ----
    float tm0 = fmaxf(s[0][0], s[1][0]), tm1 = fmaxf(s[0][1], s[1][1]);
    float tm2 = fmaxf(s[0][2], s[1][2]), tm3 = fmaxf(s[0][3], s[1][3]);
#pragma unroll
    for (int i = 4; i < 16; i += 4) {
      tm0 = fmaxf(tm0, fmaxf(s[0][i], s[1][i]));
      tm1 = fmaxf(tm1, fmaxf(s[0][i + 1], s[1][i + 1]));
      tm2 = fmaxf(tm2, fmaxf(s[0][i + 2], s[1][i + 2]));
      tm3 = fmaxf(tm3, fmaxf(s[0][i + 3], s[1][i + 3]));
    }
    float tm = fmaxf(fmaxf(tm0, tm1), fmaxf(tm2, tm3));
    tm = fmaxf(tm, __shfl_xor(tm, 32));
    if (!__all(tm <= m_run + 8.f)) {
      float mnew = fmaxf(m_run, tm);
      float corr = __builtin_amdgcn_exp2f(m_run - mnew);
      l_run *= corr;
#pragma unroll
      for (int d0 = 0; d0 < 2; ++d0)
#pragma unroll
        for (int i = 0; i < 16; ++i) acc[d0][i] *= corr;
      m_run = mnew;
    }
    float ts0 = 0.f, ts1 = 0.f, ts2 = 0.f, ts3 = 0.f;
#pragma unroll
    for (int kvh = 0; kvh < 2; ++kvh)
#pragma unroll
      for (int i = 0; i < 16; i += 4) {
        float p0 = __builtin_amdgcn_exp2f(s[kvh][i] - m_run);
        float p1 = __builtin_amdgcn_exp2f(s[kvh][i + 1] - m_run);
        float p2 = __builtin_amdgcn_exp2f(s[kvh][i + 2] - m_run);
        float p3 = __builtin_amdgcn_exp2f(s[kvh][i + 3] - m_run);
        s[kvh][i] = p0; s[kvh][i + 1] = p1; s[kvh][i + 2] = p2; s[kvh][i + 3] = p3;
        ts0 += p0; ts1 += p1; ts2 += p2; ts3 += p3;
      }
    float ts = (ts0 + ts1) + (ts2 + ts3);
    ts += __shfl_xor(ts, 32);
    l_run += ts;

    // ---- pack P -> bf16 pairs (1 VOP3 each): pk[kvh][kp][tt], kv_local = 8*kp+4*hi+2*tt
    unsigned int pk[2][4][2];
#pragma unroll
    for (int kvh = 0; kvh < 2; ++kvh)
#pragma unroll
      for (int kp = 0; kp < 4; ++kp)
#pragma unroll
        for (int tt = 0; tt < 2; ++tt)
          pk[kvh][kp][tt] = cvt_pk_bf16(s[kvh][4 * kp + 2 * tt], s[kvh][4 * kp + 2 * tt + 1]);

    // ---- PV: per kk build B-frag (P^T) via shfl_xor(32), then 2 mfma ----
    __builtin_amdgcn_s_setprio(1);
#pragma unroll
    for (int kk = 0; kk < 4; ++kk) {
      const int kvh = kk >> 1, kb = kk & 1;
      union { unsigned w[4]; bf16x8 v; } bw;
#pragma unroll
      for (int tt = 0; tt < 2; ++tt) {
        unsigned A0 = pk[kvh][2 * kb][tt];
        unsigned A1 = pk[kvh][2 * kb + 1][tt];
        unsigned S = (unsigned)__shfl_xor((int)(hi ? A0 : A1), 32);
        bw.w[tt] = hi ? S : A0;
        bw.w[2 + tt] = hi ? A1 : S;
      }
      const char* vbase = bV + (2 * kk + hi) * 1024;
      bf16x8 vf0 = *(const bf16x8*)(vbase + lq * 16);
      bf16x8 vf1 = *(const bf16x8*)(vbase + (32 + lq) * 16);
      acc[0] = mfma32(vf0, bw.v, acc[0]);
      acc[1] = mfma32(vf1, bw.v, acc[1]);
    }
    __builtin_amdgcn_s_setprio(0);
    __syncthreads();
    buf ^= 1;
  }
#undef STAGE_KV

  // ---- merge the two KV halves (exact flash combine) through aliased LDS ----
  if (wv >= 4) {
    float* cp = sm.cmb[w4][l];
#pragma unroll
    for (int d0 = 0; d0 < 2; ++d0)
#pragma unroll
      for (int i = 0; i < 16; ++i) cp[d0 * 16 + i] = acc[d0][i];
    cp[32] = m_run;
    cp[33] = l_run;
  }
  __syncthreads();
  if (wv < 4) {
    const float* cp = sm.cmb[w4][l];
    float m1 = cp[32], l1 = cp[33];
    float mm = fmaxf(m_run, m1);
    float c0 = __builtin_amdgcn_exp2f(m_run - mm);
    float c1 = __builtin_amdgcn_exp2f(m1 - mm);
    float invl = 1.f / (l_run * c0 + l1 * c1);
    float s0 = c0 * invl, s1 = c1 * invl;
    // O^T regs -> AO[q][h*64+d], d = 32*d0 + 8*rg + 4*hi + rr
#pragma unroll
    for (int d0 = 0; d0 < 2; ++d0)
#pragma unroll
      for (int rg = 0; rg < 4; ++rg) {
        float v0 = acc[d0][4 * rg + 0] * s0 + cp[d0 * 16 + 4 * rg + 0] * s1;
        float v1 = acc[d0][4 * rg + 1] * s0 + cp[d0 * 16 + 4 * rg + 1] * s1;
        float v2 = acc[d0][4 * rg + 2] * s0 + cp[d0 * 16 + 4 * rg + 2] * s1;
        float v3 = acc[d0][4 * rg + 3] * s0 + cp[d0 * 16 + 4 * rg + 3] * s1;
        u32x2 o;
        o.x = cvt_pk_bf16(v0, v1);
        o.y = cvt_pk_bf16(v2, v3);
        int d = 32 * d0 + 8 * rg + 4 * hi;
        *(u32x2*)(AO + (size_t)qrow * 1024 + h * 64 + d) = o;
      }
  }
}

// ---------------- launch ----------------

extern "C" void kernel_launch(void* const* d_in, const int* in_sizes, int n_in,
                              void* d_out, int out_size, void* d_ws, size_t ws_size,
                              hipStream_t stream) {
  const float* x = (const float*)d_in[0];
  const float* ctx = (const float*)d_in[1];
  const float* Wq = (const float*)d_in[2];
  const float* Wk = (const float*)d_in[3];
  const float* Wv = (const float*)d_in[4];
  const float* Wu = (const float*)d_in[5];
  const float* bu = (const float*)d_in[6];
  const float* qg = (const float*)d_in[7];
  const float* qb = (const float*)d_in[8];
  const float* kg = (const float*)d_in[9];
  const float* kb = (const float*)d_in[10];
  float* out = (float*)d_out;

  char* w = (char*)d_ws;
  u16* XCB = (u16*)(w);                       // 16 MB: xc bf16 [B,T,E]
  u16* WQB = (u16*)(w + ((size_t)16 << 20));  // 8 MB: Wq,Wk,Wv,Wu bf16 contiguous
  u16* QBB = (u16*)(w + ((size_t)24 << 20));  // 8 MB
  u16* KBB = (u16*)(w + ((size_t)32 << 20));  // 16 MB
  u16* VT = (u16*)(w + ((size_t)48 << 20));   // 16 MB
  u16* AO = (u16*)(w + ((size_t)64 << 20));   // 8 MB  (total 72 MB)

  const float invs = 0.17677669529663687f;          // 1024^-0.25
  const float invs_l2e = invs * 1.44269504088896f;  // fold log2(e) into Q for exp2 softmax

  cast_concat<<<2048, 256, 0, stream>>>(x, ctx, XCB);
  cast_w<<<1024, 256, 0, stream>>>(Wq, Wk, Wv, Wu, WQB);

  gemm_qkv<<<dim3(64, 24), 256, 0, stream>>>(XCB, WQB, QBB, KBB, VT,
                                             qg, qb, kg, kb, invs_l2e, invs);

  attn_kernel<<<dim3(8, 16, 4), 512, 0, stream>>>(QBB, KBB, VT, AO);

  gemm_u64<<<dim3(64, 8), 256, 0, stream>>>(AO, WQB + ((size_t)3 << 20), out, bu);
}